// Round 3
// baseline (452.600 us; speedup 1.0000x reference)
//
#include <hip/hip_runtime.h>

typedef unsigned short u16;
typedef unsigned int   u32;

#define IM_H    240
#define IM_W    320
#define ENV_ROW 120
#define ENV_COL 160
#define NPIX    19200           // ENV_ROW*ENV_COL
#define EH      8
#define EW      16
#define NGRIDS  384
#define BATCH   2

#define ACC_SIZE (BATCH*3*NGRIDS*NPIX)      // 44,236,800
#define MASK_OFF ACC_SIZE
#define MEAN_OFF (ACC_SIZE + BATCH*NPIX)

// workspace layout (floats)
#define WS_SUM       0          // B*3*NGRIDS = 2304
#define WS_MASKSUM   2304       // B
#define WS_CENTERS   2308       // B*NGRIDS*3 = 2304
#define WS_ZERO_F    2306

__device__ __forceinline__ float bf2f(u16 u) {
    return __uint_as_float(((u32)u) << 16);
}
__device__ __forceinline__ u16 f2bf(float f) {
    u32 x = __float_as_uint(f);
    x += 0x7fffu + ((x >> 16) & 1u);        // RNE
    return (u16)(x >> 16);
}

// ---------------------------------------------------------------- mask kernel
__global__ __launch_bounds__(256) void k_mask(const float* __restrict__ depth,
                                              float* __restrict__ out,
                                              float* __restrict__ masksum) {
    int g = blockIdx.x * 256 + threadIdx.x;     // < 38400, waves never cross b
    int b = g / NPIX;
    int p = g % NPIX;
    int r = p / ENV_COL, c = p % ENV_COL;
    float d = depth[(size_t)(b * IM_H + 2 * r) * IM_W + 2 * c];
    float m = (-d < -0.1f) ? 1.0f : 0.0f;
    out[MASK_OFF + g] = m;
    float s = m;
    #pragma unroll
    for (int off = 32; off >= 1; off >>= 1) s += __shfl_xor(s, off);
    if ((threadIdx.x & 63) == 0) atomicAdd(&masksum[b], s);
}

// ------------------------------------------------------------- centers kernel
__global__ __launch_bounds__(256) void k_centers(const float* __restrict__ layout,
                                                 const float* __restrict__ camR,
                                                 float* __restrict__ cen) {
    int t = blockIdx.x * 256 + threadIdx.x;
    if (t >= BATCH * NGRIDS) return;
    int b = t / NGRIDS, n = t % NGRIDS;
    int f = n >> 6, gi = (n >> 3) & 7, hj = n & 7;
    const int B0[6] = {3, 7, 4, 6, 7, 7};
    const int B1[6] = {2, 6, 5, 2, 6, 3};
    const int B2[6] = {0, 4, 0, 5, 3, 4};
    int t0 = B0[f], t1 = B1[f], t2 = B2[f];
    float cw[3];
    #pragma unroll
    for (int j = 0; j < 3; ++j) {
        float o  = layout[(b * 8 + t0) * 3 + j];
        float b1 = (layout[(b * 8 + t1) * 3 + j] - o) * 0.125f;
        float b2 = (layout[(b * 8 + t2) * 3 + j] - o) * 0.125f;
        cw[j] = b1 * ((float)gi + 0.5f) + b2 * ((float)hj + 0.5f) + o;
    }
    float v[3];
    #pragma unroll
    for (int i = 0; i < 3; ++i) {           // v = R^T * cw
        v[i] = camR[b * 9 + 0 * 3 + i] * cw[0]
             + camR[b * 9 + 1 * 3 + i] * cw[1]
             + camR[b * 9 + 2 * 3 + i] * cw[2];
    }
    // apply M12^T: (v_z, v_y, -v_x)
    cen[t * 3 + 0] = v[2];
    cen[t * 3 + 1] = v[1];
    cen[t * 3 + 2] = -v[0];
}

// ---------------------------------------------------------------- main kernel
// block = 32 consecutive pixels (one env row segment) x 96 centers
// thread: pix = tid&31, slot = tid>>5 (8-way n split), 12 iterations
__global__ __launch_bounds__(256, 4) void k_main(
        const float* __restrict__ normal,
        const float* __restrict__ depth,
        const float* __restrict__ envm,
        const float* __restrict__ camK,
        const float* __restrict__ cen,
        float* __restrict__ wsum,
        float* __restrict__ out) {

    __shared__ __align__(16) u16 env_s[EH * EW * 32 * 4]; // [texel][pix][ch4] 32 KB
    __shared__ float pgeo[32][17];                        // pt(3) Ainv(9) mask(1)
    __shared__ float cen_s[96 * 3];

    const int tid = threadIdx.x;
    const int bid = blockIdx.x;
    const int b   = bid / 2400;
    const int rem = bid % 2400;
    const int pg  = rem >> 2;       // 0..599 pixel group
    const int nc  = rem & 3;        // 0..3 n-chunk
    const int p0  = pg * 32;
    const int n0  = nc * 96;

    // ---- stage env tile (f32 -> bf16 LDS).  Mapping: consecutive lanes =
    // consecutive PIXELS so LDS store banks are (2*lane mod 32) -> 2-way only.
    // 3072 float4 loads: ci = [pix(5b) | og(5b) | ch(2b)]
    #pragma unroll
    for (int k = 0; k < 12; ++k) {
        int ci  = tid + k * 256;          // 0..3071
        int pix = ci & 31;
        int q   = ci >> 5;                // 0..95
        int ch  = q >> 5;                 // 0..2
        int og  = q & 31;                 // texel group (4 texels)
        const float4 v = *reinterpret_cast<const float4*>(
            &envm[((size_t)(b * 3 + ch) * NPIX + p0 + pix) * 128 + og * 4]);
        int s = (og * 4) * 128 + pix * 4 + ch;
        env_s[s + 0 * 128] = f2bf(v.x);
        env_s[s + 1 * 128] = f2bf(v.y);
        env_s[s + 2 * 128] = f2bf(v.z);
        env_s[s + 3 * 128] = f2bf(v.w);
    }

    // ---- stage centers (96 x 3 floats)
    for (int idx = tid; idx < 288; idx += 256)
        cen_s[idx] = cen[((size_t)b * NGRIDS + n0) * 3 + idx];

    // ---- per-pixel geometry (32 threads)
    if (tid < 32) {
        int p = p0 + tid;
        int r = p / ENV_COL, c = p % ENV_COL;
        float nv[3];
        #pragma unroll
        for (int ch = 0; ch < 3; ++ch) {
            const float* np_ = &normal[((size_t)(b * 3 + ch) * IM_H + 2 * r) * IM_W + 2 * c];
            nv[ch] = 0.25f * (np_[0] + np_[1] + np_[IM_W] + np_[IM_W + 1]);
        }
        float s2 = nv[0]*nv[0] + nv[1]*nv[1] + nv[2]*nv[2];
        s2 = fminf(fmaxf(s2, 1e-6f), 1.0f);
        float inv = 1.0f / sqrtf(s2);
        nv[0] *= inv; nv[1] *= inv; nv[2] *= inv;
        // camy = normalize(up - (up.n) n), up=(0,1,0)
        float ty0 = -nv[1]*nv[0], ty1 = 1.0f - nv[1]*nv[1], ty2 = -nv[1]*nv[2];
        float tn = fmaxf(sqrtf(ty0*ty0 + ty1*ty1 + ty2*ty2), 1e-12f);
        float cy0 = ty0/tn, cy1 = ty1/tn, cy2 = ty2/tn;
        // camx = -normalize(cross(camy, n))
        float cr0 = cy1*nv[2] - cy2*nv[1];
        float cr1 = cy2*nv[0] - cy0*nv[2];
        float cr2 = cy0*nv[1] - cy1*nv[0];
        float cnm = fmaxf(sqrtf(cr0*cr0 + cr1*cr1 + cr2*cr2), 1e-12f);
        float cx0 = -cr0/cnm, cx1 = -cr1/cnm, cx2 = -cr2/cnm;
        // A = [camx camy n] columns, + 1e-6 I ; invert (adjugate)
        float a = cx0 + 1e-6f, bb = cy0,         cc = nv[0];
        float d = cx1,         e  = cy1 + 1e-6f, f  = nv[1];
        float g2 = cx2,        h  = cy2,         i  = nv[2] + 1e-6f;
        float c00 = e*i - f*h,   c01 = f*g2 - d*i,  c02 = d*h - e*g2;
        float c10 = cc*h - bb*i, c11 = a*i - cc*g2, c12 = bb*g2 - a*h;
        float c20 = bb*f - cc*e, c21 = cc*d - a*f,  c22 = a*e - bb*d;
        float rdet = 1.0f / (a*c00 + bb*c01 + cc*c02);
        float K00 = camK[b * 9 + 0];
        float K02 = camK[b * 9 + 2];
        float fpix = K00 * (IM_W / 2.0f) / K02;
        float z = -depth[((size_t)b * IM_H + 2 * r) * IM_W + 2 * c];
        float px = -((2.0f * c) - IM_W / 2.0f) / fpix * z;
        float py =  ((2.0f * r) - IM_H / 2.0f) / fpix * z;
        float mask = (z < -0.1f) ? 1.0f : 0.0f;
        pgeo[tid][0] = px;  pgeo[tid][1] = py;  pgeo[tid][2] = z;
        pgeo[tid][3] = c00*rdet; pgeo[tid][4]  = c10*rdet; pgeo[tid][5]  = c20*rdet;
        pgeo[tid][6] = c01*rdet; pgeo[tid][7]  = c11*rdet; pgeo[tid][8]  = c21*rdet;
        pgeo[tid][9] = c02*rdet; pgeo[tid][10] = c12*rdet; pgeo[tid][11] = c22*rdet;
        pgeo[tid][12] = mask;
    }

    __syncthreads();

    const int pix  = tid & 31;
    const int slot = tid >> 5;
    const float ptx = pgeo[pix][0], pty = pgeo[pix][1], ptz = pgeo[pix][2];
    const float A0 = pgeo[pix][3], A1 = pgeo[pix][4],  A2 = pgeo[pix][5];
    const float A3 = pgeo[pix][6], A4 = pgeo[pix][7],  A5 = pgeo[pix][8];
    const float A6 = pgeo[pix][9], A7 = pgeo[pix][10], A8 = pgeo[pix][11];
    const float mscale = pgeo[pix][12] * 0.1f;

    for (int it = 0; it < 12; ++it) {
        const int nl = it * 8 + slot;                  // 0..95
        const int n  = n0 + nl;
        const float vx = cen_s[nl * 3 + 0] - ptx;
        const float vy = cen_s[nl * 3 + 1] - pty;
        const float vz = cen_s[nl * 3 + 2] - ptz;
        float lx = A0 * vx + A1 * vy + A2 * vz;
        float ly = A3 * vx + A4 * vy + A5 * vz;
        float lz = A6 * vx + A7 * vy + A8 * vz;
        float rn = rsqrtf(lx * lx + ly * ly + lz * lz);
        float ct = fminf(fmaxf(lz * rn, -1.0f), 1.0f);
        float theta = acosf(ct);
        float phi = atan2f(ly, lx);                    // sin_t>0 divides out
        float az = phi * 2.54647908947032537f + 7.5f;  // phi*(8/pi)+7.5
        float el = theta * 5.09295817894065074f - 0.5f;// theta*(16/pi)-0.5
        float x = fminf(fmaxf(az, 0.0f), 15.0f);
        float y = fminf(fmaxf(el, 0.0f), 7.0f);
        float x0f = floorf(x), y0f = floorf(y);
        float wx = x - x0f, wy = y - y0f;
        int ix0 = (int)x0f, iy0 = (int)y0f;
        int ix1 = min(ix0 + 1, 15), iy1 = min(iy0 + 1, 7);
        int b00 = ((iy0 * 16 + ix0) * 32 + pix) * 4;
        int b01 = ((iy0 * 16 + ix1) * 32 + pix) * 4;
        int b10 = ((iy1 * 16 + ix0) * 32 + pix) * 4;
        int b11 = ((iy1 * 16 + ix1) * 32 + pix) * 4;
        ushort4 q00 = *reinterpret_cast<ushort4*>(&env_s[b00]);
        ushort4 q01 = *reinterpret_cast<ushort4*>(&env_s[b01]);
        ushort4 q10 = *reinterpret_cast<ushort4*>(&env_s[b10]);
        ushort4 q11 = *reinterpret_cast<ushort4*>(&env_s[b11]);
        float w00 = (1.0f - wy) * (1.0f - wx);
        float w01 = (1.0f - wy) * wx;
        float w10 = wy * (1.0f - wx);
        float w11 = wy * wx;
        float v0 = (w00*bf2f(q00.x) + w01*bf2f(q01.x) + w10*bf2f(q10.x) + w11*bf2f(q11.x)) * mscale;
        float v1 = (w00*bf2f(q00.y) + w01*bf2f(q01.y) + w10*bf2f(q10.y) + w11*bf2f(q11.y)) * mscale;
        float v2 = (w00*bf2f(q00.z) + w01*bf2f(q01.z) + w10*bf2f(q10.z) + w11*bf2f(q11.z)) * mscale;

        size_t obase = ((size_t)(b * 3 + 0) * NGRIDS + n) * NPIX + p0 + pix;
        out[obase]                                  = v0;
        out[obase + (size_t)NGRIDS * NPIX]          = v1;
        out[obase + (size_t)2 * NGRIDS * NPIX]      = v2;

        // reduce over 32 pixels (stays within half-wave: xor masks < 32)
        float s0 = v0, s1 = v1, s2v = v2;
        #pragma unroll
        for (int m = 16; m >= 1; m >>= 1) {
            s0  += __shfl_xor(s0, m);
            s1  += __shfl_xor(s1, m);
            s2v += __shfl_xor(s2v, m);
        }
        if (pix == 0) {
            atomicAdd(&wsum[(b * 3 + 0) * NGRIDS + n], s0);
            atomicAdd(&wsum[(b * 3 + 1) * NGRIDS + n], s1);
            atomicAdd(&wsum[(b * 3 + 2) * NGRIDS + n], s2v);
        }
    }
}

// ------------------------------------------------------------- finalize mean
__global__ __launch_bounds__(256) void k_final(const float* __restrict__ wsum,
                                               const float* __restrict__ masksum,
                                               float* __restrict__ out) {
    int t = blockIdx.x * 256 + threadIdx.x;
    if (t >= BATCH * NGRIDS * 3) return;
    int b = t / (NGRIDS * 3);
    int r = t % (NGRIDS * 3);
    int n = r / 3, ch = r % 3;
    float mval = wsum[(b * 3 + ch) * NGRIDS + n] / (masksum[b] + 1e-6f);
    out[MEAN_OFF + t] = mval;           // mean layout (B, NGRIDS, 3)
}

extern "C" void kernel_launch(void* const* d_in, const int* in_sizes, int n_in,
                              void* d_out, int out_size, void* d_ws, size_t ws_size,
                              hipStream_t stream) {
    const float* normal = (const float*)d_in[0];
    const float* depth  = (const float*)d_in[1];
    const float* envm   = (const float*)d_in[2];
    const float* camK   = (const float*)d_in[3];
    const float* camR   = (const float*)d_in[4];
    const float* layout = (const float*)d_in[5];
    float* out = (float*)d_out;
    float* ws  = (float*)d_ws;

    hipMemsetAsync(ws, 0, WS_ZERO_F * sizeof(float), stream);
    k_mask<<<dim3(150), dim3(256), 0, stream>>>(depth, out, ws + WS_MASKSUM);
    k_centers<<<dim3(3), dim3(256), 0, stream>>>(layout, camR, ws + WS_CENTERS);
    k_main<<<dim3(4800), dim3(256), 0, stream>>>(normal, depth, envm, camK,
                                                 ws + WS_CENTERS, ws + WS_SUM, out);
    k_final<<<dim3(9), dim3(256), 0, stream>>>(ws + WS_SUM, ws + WS_MASKSUM, out);
}

// Round 4
// 452.176 us; speedup vs baseline: 1.0009x; 1.0009x over previous
//
#include <hip/hip_runtime.h>

typedef unsigned short u16;
typedef unsigned int   u32;

#define IM_H    240
#define IM_W    320
#define ENV_ROW 120
#define ENV_COL 160
#define NPIX    19200           // ENV_ROW*ENV_COL
#define EH      8
#define EW      16
#define NGRIDS  384
#define BATCH   2

#define ACC_SIZE (BATCH*3*NGRIDS*NPIX)      // 44,236,800
#define MASK_OFF ACC_SIZE
#define MEAN_OFF (ACC_SIZE + BATCH*NPIX)

// workspace layout (floats)
#define WS_SUM       0          // B*3*NGRIDS = 2304
#define WS_MASKSUM   2304       // B
#define WS_CENTERS   2308       // B*NGRIDS*3 = 2304
#define WS_ZERO_F    2306

#define PI_F  3.14159265358979f
#define PI_2F 1.57079632679490f

__device__ __forceinline__ float bf2f(u16 u) {
    return __uint_as_float(((u32)u) << 16);
}
__device__ __forceinline__ u16 f2bf(float f) {
    u32 x = __float_as_uint(f);
    x += 0x7fffu + ((x >> 16) & 1u);        // RNE
    return (u16)(x >> 16);
}

// acos via sqrt(1-|x|)*poly, max err ~6.8e-5 rad (A&S 4.4.45)
__device__ __forceinline__ float fast_acos(float x) {
    float ax = fabsf(x);
    float s  = sqrtf(fmaxf(1.0f - ax, 0.0f));
    float p  = ((-0.0187293f * ax + 0.0742610f) * ax - 0.2121144f) * ax + 1.5707288f;
    float r  = s * p;
    return (x < 0.0f) ? (PI_F - r) : r;
}

// full-quadrant atan2, Hastings deg-9 minimax on [0,1], err ~1e-5 rad
__device__ __forceinline__ float fast_atan2(float y, float x) {
    float ax = fabsf(x), ay = fabsf(y);
    float mx = fmaxf(ax, ay), mn = fminf(ax, ay);
    float t  = mn * __builtin_amdgcn_rcpf(fmaxf(mx, 1e-37f));
    float t2 = t * t;
    float p  = ((((0.0208351f * t2 - 0.0851330f) * t2 + 0.1801410f) * t2
                 - 0.3302995f) * t2 + 0.9998660f) * t;
    p = (ay > ax) ? (PI_2F - p) : p;
    p = (x < 0.0f) ? (PI_F - p) : p;
    return __builtin_copysignf(p, y);
}

// ------------------------------------------------------------- centers kernel
__global__ __launch_bounds__(256) void k_centers(const float* __restrict__ layout,
                                                 const float* __restrict__ camR,
                                                 float* __restrict__ cen) {
    int t = blockIdx.x * 256 + threadIdx.x;
    if (t >= BATCH * NGRIDS) return;
    int b = t / NGRIDS, n = t % NGRIDS;
    int f = n >> 6, gi = (n >> 3) & 7, hj = n & 7;
    const int B0[6] = {3, 7, 4, 6, 7, 7};
    const int B1[6] = {2, 6, 5, 2, 6, 3};
    const int B2[6] = {0, 4, 0, 5, 3, 4};
    int t0 = B0[f], t1 = B1[f], t2 = B2[f];
    float cw[3];
    #pragma unroll
    for (int j = 0; j < 3; ++j) {
        float o  = layout[(b * 8 + t0) * 3 + j];
        float b1 = (layout[(b * 8 + t1) * 3 + j] - o) * 0.125f;
        float b2 = (layout[(b * 8 + t2) * 3 + j] - o) * 0.125f;
        cw[j] = b1 * ((float)gi + 0.5f) + b2 * ((float)hj + 0.5f) + o;
    }
    float v[3];
    #pragma unroll
    for (int i = 0; i < 3; ++i) {           // v = R^T * cw
        v[i] = camR[b * 9 + 0 * 3 + i] * cw[0]
             + camR[b * 9 + 1 * 3 + i] * cw[1]
             + camR[b * 9 + 2 * 3 + i] * cw[2];
    }
    // apply M12^T: (v_z, v_y, -v_x)
    cen[t * 3 + 0] = v[2];
    cen[t * 3 + 1] = v[1];
    cen[t * 3 + 2] = -v[0];
}

// ---------------------------------------------------------------- main kernel
// block = 32 consecutive pixels (one env row segment) x 96 centers
// thread: pix = tid&31, slot = tid>>5 (8-way n split), 12 iterations
__global__ __launch_bounds__(256, 4) void k_main(
        const float* __restrict__ normal,
        const float* __restrict__ depth,
        const float* __restrict__ envm,
        const float* __restrict__ camK,
        const float* __restrict__ cen,
        float* __restrict__ wsum,
        float* __restrict__ masksum,
        float* __restrict__ out) {

    __shared__ __align__(16) u16 env_s[EH * EW * 32 * 4]; // [texel][pix][ch4] 32 KB
    __shared__ float pgeo[32][17];                        // pt(3) Ainv(9) mask(1)
    __shared__ __align__(16) float cen_s[96 * 4];         // padded float4

    const int tid = threadIdx.x;
    const int bid = blockIdx.x;
    const int b   = bid / 2400;
    const int rem = bid % 2400;
    const int pg  = rem >> 2;       // 0..599 pixel group
    const int nc  = rem & 3;        // 0..3 n-chunk
    const int p0  = pg * 32;
    const int n0  = nc * 96;

    // ---- stage env tile (f32 -> bf16 LDS).  Lanes = consecutive PIXELS so
    // LDS store banks are (2*lane mod 32) -> 2-way only (free, m136).
    #pragma unroll
    for (int k = 0; k < 12; ++k) {
        int ci  = tid + k * 256;          // 0..3071
        int pix = ci & 31;
        int q   = ci >> 5;                // 0..95
        int ch  = q >> 5;                 // 0..2
        int og  = q & 31;                 // texel group (4 texels)
        const float4 v = *reinterpret_cast<const float4*>(
            &envm[((size_t)(b * 3 + ch) * NPIX + p0 + pix) * 128 + og * 4]);
        int s = (og * 4) * 128 + pix * 4 + ch;
        env_s[s + 0 * 128] = f2bf(v.x);
        env_s[s + 1 * 128] = f2bf(v.y);
        env_s[s + 2 * 128] = f2bf(v.z);
        env_s[s + 3 * 128] = f2bf(v.w);
    }

    // ---- stage centers (96 x float4, w-padded)
    for (int idx = tid; idx < 384; idx += 256) {
        int nl = idx >> 2, j = idx & 3;
        cen_s[idx] = (j < 3) ? cen[((size_t)b * NGRIDS + n0 + nl) * 3 + j] : 0.0f;
    }

    // ---- per-pixel geometry (32 threads) + mask output (nc==0 blocks)
    if (tid < 32) {
        int p = p0 + tid;
        int r = p / ENV_COL, c = p % ENV_COL;
        float nv[3];
        #pragma unroll
        for (int ch = 0; ch < 3; ++ch) {
            const float* np_ = &normal[((size_t)(b * 3 + ch) * IM_H + 2 * r) * IM_W + 2 * c];
            nv[ch] = 0.25f * (np_[0] + np_[1] + np_[IM_W] + np_[IM_W + 1]);
        }
        float s2 = nv[0]*nv[0] + nv[1]*nv[1] + nv[2]*nv[2];
        s2 = fminf(fmaxf(s2, 1e-6f), 1.0f);
        float inv = 1.0f / sqrtf(s2);
        nv[0] *= inv; nv[1] *= inv; nv[2] *= inv;
        // camy = normalize(up - (up.n) n), up=(0,1,0)
        float ty0 = -nv[1]*nv[0], ty1 = 1.0f - nv[1]*nv[1], ty2 = -nv[1]*nv[2];
        float tn = fmaxf(sqrtf(ty0*ty0 + ty1*ty1 + ty2*ty2), 1e-12f);
        float cy0 = ty0/tn, cy1 = ty1/tn, cy2 = ty2/tn;
        // camx = -normalize(cross(camy, n))
        float cr0 = cy1*nv[2] - cy2*nv[1];
        float cr1 = cy2*nv[0] - cy0*nv[2];
        float cr2 = cy0*nv[1] - cy1*nv[0];
        float cnm = fmaxf(sqrtf(cr0*cr0 + cr1*cr1 + cr2*cr2), 1e-12f);
        float cx0 = -cr0/cnm, cx1 = -cr1/cnm, cx2 = -cr2/cnm;
        // A = [camx camy n] columns, + 1e-6 I ; invert (adjugate)
        float a = cx0 + 1e-6f, bb = cy0,         cc = nv[0];
        float d = cx1,         e  = cy1 + 1e-6f, f  = nv[1];
        float g2 = cx2,        h  = cy2,         i  = nv[2] + 1e-6f;
        float c00 = e*i - f*h,   c01 = f*g2 - d*i,  c02 = d*h - e*g2;
        float c10 = cc*h - bb*i, c11 = a*i - cc*g2, c12 = bb*g2 - a*h;
        float c20 = bb*f - cc*e, c21 = cc*d - a*f,  c22 = a*e - bb*d;
        float rdet = 1.0f / (a*c00 + bb*c01 + cc*c02);
        float K00 = camK[b * 9 + 0];
        float K02 = camK[b * 9 + 2];
        float fpix = K00 * (IM_W / 2.0f) / K02;
        float z = -depth[((size_t)b * IM_H + 2 * r) * IM_W + 2 * c];
        float px = -((2.0f * c) - IM_W / 2.0f) / fpix * z;
        float py =  ((2.0f * r) - IM_H / 2.0f) / fpix * z;
        float mask = (z < -0.1f) ? 1.0f : 0.0f;
        pgeo[tid][0] = px;  pgeo[tid][1] = py;  pgeo[tid][2] = z;
        pgeo[tid][3] = c00*rdet; pgeo[tid][4]  = c10*rdet; pgeo[tid][5]  = c20*rdet;
        pgeo[tid][6] = c01*rdet; pgeo[tid][7]  = c11*rdet; pgeo[tid][8]  = c21*rdet;
        pgeo[tid][9] = c02*rdet; pgeo[tid][10] = c12*rdet; pgeo[tid][11] = c22*rdet;
        pgeo[tid][12] = mask;
        if (nc == 0) {                       // fold old k_mask in here
            out[MASK_OFF + (size_t)b * NPIX + p] = mask;
            float s = mask;
            #pragma unroll
            for (int m = 16; m >= 1; m >>= 1) s += __shfl_xor(s, m);
            if (tid == 0) atomicAdd(&masksum[b], s);
        }
    }

    __syncthreads();

    const int pix  = tid & 31;
    const int slot = tid >> 5;
    const float ptx = pgeo[pix][0], pty = pgeo[pix][1], ptz = pgeo[pix][2];
    const float A0 = pgeo[pix][3], A1 = pgeo[pix][4],  A2 = pgeo[pix][5];
    const float A3 = pgeo[pix][6], A4 = pgeo[pix][7],  A5 = pgeo[pix][8];
    const float A6 = pgeo[pix][9], A7 = pgeo[pix][10], A8 = pgeo[pix][11];
    const float mscale = pgeo[pix][12] * 0.1f;

    #pragma unroll 4
    for (int it = 0; it < 12; ++it) {
        const int nl = it * 8 + slot;                  // 0..95
        const int n  = n0 + nl;
        const float4 cc4 = *reinterpret_cast<const float4*>(&cen_s[nl * 4]);
        const float vx = cc4.x - ptx;
        const float vy = cc4.y - pty;
        const float vz = cc4.z - ptz;
        float lx = A0 * vx + A1 * vy + A2 * vz;
        float ly = A3 * vx + A4 * vy + A5 * vz;
        float lz = A6 * vx + A7 * vy + A8 * vz;
        float rn = __builtin_amdgcn_rsqf(lx * lx + ly * ly + lz * lz);
        float ct = fminf(fmaxf(lz * rn, -1.0f), 1.0f);
        float theta = fast_acos(ct);
        float phi = fast_atan2(ly, lx);                // sin_t>0 divides out
        float az = phi * 2.54647908947032537f + 7.5f;  // phi*(8/pi)+7.5
        float el = theta * 5.09295817894065074f - 0.5f;// theta*(16/pi)-0.5
        float x = fminf(fmaxf(az, 0.0f), 15.0f);
        float y = fminf(fmaxf(el, 0.0f), 7.0f);
        float x0f = floorf(x), y0f = floorf(y);
        float wx = x - x0f, wy = y - y0f;
        int ix0 = (int)x0f, iy0 = (int)y0f;
        int ix1 = min(ix0 + 1, 15), iy1 = min(iy0 + 1, 7);
        int pb  = pix * 4;
        int b00 = ((iy0 * 16 + ix0) * 32) * 4 + pb;
        int b01 = ((iy0 * 16 + ix1) * 32) * 4 + pb;
        int b10 = ((iy1 * 16 + ix0) * 32) * 4 + pb;
        int b11 = ((iy1 * 16 + ix1) * 32) * 4 + pb;
        ushort4 q00 = *reinterpret_cast<ushort4*>(&env_s[b00]);
        ushort4 q01 = *reinterpret_cast<ushort4*>(&env_s[b01]);
        ushort4 q10 = *reinterpret_cast<ushort4*>(&env_s[b10]);
        ushort4 q11 = *reinterpret_cast<ushort4*>(&env_s[b11]);
        float w00 = (1.0f - wy) * (1.0f - wx);
        float w01 = (1.0f - wy) * wx;
        float w10 = wy * (1.0f - wx);
        float w11 = wy * wx;
        float v0 = (w00*bf2f(q00.x) + w01*bf2f(q01.x) + w10*bf2f(q10.x) + w11*bf2f(q11.x)) * mscale;
        float v1 = (w00*bf2f(q00.y) + w01*bf2f(q01.y) + w10*bf2f(q10.y) + w11*bf2f(q11.y)) * mscale;
        float v2 = (w00*bf2f(q00.z) + w01*bf2f(q01.z) + w10*bf2f(q10.z) + w11*bf2f(q11.z)) * mscale;

        size_t obase = ((size_t)(b * 3 + 0) * NGRIDS + n) * NPIX + p0 + pix;
        out[obase]                             = v0;
        out[obase + (size_t)NGRIDS * NPIX]     = v1;
        out[obase + (size_t)2 * NGRIDS * NPIX] = v2;

        // reduce over 32 pixels (xor masks < 32 stay within half-wave;
        // masks 1..8 compile to DPP row ops = VALU, only 16 goes via DS)
        float s0 = v0, s1 = v1, s2v = v2;
        #pragma unroll
        for (int m = 16; m >= 1; m >>= 1) {
            s0  += __shfl_xor(s0, m);
            s1  += __shfl_xor(s1, m);
            s2v += __shfl_xor(s2v, m);
        }
        if (pix == 0) {
            atomicAdd(&wsum[(b * 3 + 0) * NGRIDS + n], s0);
            atomicAdd(&wsum[(b * 3 + 1) * NGRIDS + n], s1);
            atomicAdd(&wsum[(b * 3 + 2) * NGRIDS + n], s2v);
        }
    }
}

// ------------------------------------------------------------- finalize mean
__global__ __launch_bounds__(256) void k_final(const float* __restrict__ wsum,
                                               const float* __restrict__ masksum,
                                               float* __restrict__ out) {
    int t = blockIdx.x * 256 + threadIdx.x;
    if (t >= BATCH * NGRIDS * 3) return;
    int b = t / (NGRIDS * 3);
    int r = t % (NGRIDS * 3);
    int n = r / 3, ch = r % 3;
    float mval = wsum[(b * 3 + ch) * NGRIDS + n] / (masksum[b] + 1e-6f);
    out[MEAN_OFF + t] = mval;           // mean layout (B, NGRIDS, 3)
}

extern "C" void kernel_launch(void* const* d_in, const int* in_sizes, int n_in,
                              void* d_out, int out_size, void* d_ws, size_t ws_size,
                              hipStream_t stream) {
    const float* normal = (const float*)d_in[0];
    const float* depth  = (const float*)d_in[1];
    const float* envm   = (const float*)d_in[2];
    const float* camK   = (const float*)d_in[3];
    const float* camR   = (const float*)d_in[4];
    const float* layout = (const float*)d_in[5];
    float* out = (float*)d_out;
    float* ws  = (float*)d_ws;

    hipMemsetAsync(ws, 0, WS_ZERO_F * sizeof(float), stream);
    k_centers<<<dim3(3), dim3(256), 0, stream>>>(layout, camR, ws + WS_CENTERS);
    k_main<<<dim3(4800), dim3(256), 0, stream>>>(normal, depth, envm, camK,
                                                 ws + WS_CENTERS, ws + WS_SUM,
                                                 ws + WS_MASKSUM, out);
    k_final<<<dim3(9), dim3(256), 0, stream>>>(ws + WS_SUM, ws + WS_MASKSUM, out);
}